// Round 11
// baseline (163.743 us; speedup 1.0000x reference)
//
#include <hip/hip_runtime.h>
#include <hip/hip_bf16.h>

#define H_NUM 16
#define D_DIM 64
#define S_LEN 2048
#define EMB   1024
#define M_TOT 4096   // B * S_LEN

typedef unsigned short u16;
typedef unsigned int   u32;
typedef __attribute__((ext_vector_type(8))) short short8;   // 8 bf16 in 4 VGPRs
typedef __attribute__((ext_vector_type(4))) float f32x4;    // MFMA C/D

__device__ __forceinline__ u32 f2bf_u(float f) {
    u32 u = __float_as_uint(f);
    return (u + 0x7fffu + ((u >> 16) & 1u)) >> 16;   // RNE, low 16 valid
}
__device__ __forceinline__ u32 pack2(float a, float b) {
    return f2bf_u(a) | (f2bf_u(b) << 16);
}
// 1-instr truncating bf16 pack: low16 = bf16(a) (RTZ), high16 = bf16(b) (RTZ)
__device__ __forceinline__ u32 pack2t(float a, float b) {
    return __builtin_amdgcn_perm(__float_as_uint(b), __float_as_uint(a),
                                 0x07060302u);
}
__device__ __forceinline__ uint4 pack8(float4 lo, float4 hi) {
    return make_uint4(pack2(lo.x, lo.y), pack2(lo.z, lo.w),
                      pack2(hi.x, hi.y), pack2(hi.z, hi.w));
}

// async global->LDS, 16B per lane; lds dest = wave-uniform base + lane*16
__device__ __forceinline__ void lds_dma16(const u16* g, u16* l) {
    __builtin_amdgcn_global_load_lds(
        (const __attribute__((address_space(1))) void*)g,
        (__attribute__((address_space(3))) void*)l, 16, 0, 0);
}

// ---------------------------------------------------------------------------
// Kernel 0: cast f32 inputs -> bf16 ws copies; seg 5 builds RoPE cos/sin table
// ---------------------------------------------------------------------------
__global__ __launch_bounds__(256) void cast_kernel(
    const float* __restrict__ x,  const float* __restrict__ Wq,
    const float* __restrict__ Wk, const float* __restrict__ Wv,
    const float* __restrict__ Wo, u16* __restrict__ ws, float2* __restrict__ tab)
{
    const int seg = blockIdx.y;
    if (seg == 5) {
        const int idx = blockIdx.x * 256 + threadIdx.x;
        if (idx < S_LEN * 32) {
            const int s = idx >> 5, d = idx & 31;
            const float ang = (float)s * __expf(-(float)d * 0.28782313662425573f);
            tab[idx] = make_float2(cosf(ang), sinf(ang));
        }
        return;
    }
    const float* src = (seg == 0) ? x : (seg == 1) ? Wq : (seg == 2) ? Wk
                     : (seg == 3) ? Wv : Wo;
    u16* dst = (seg == 0) ? ws : ws + (3 + seg) * 1048576;   // xb@0, W*@4M..7M
    const int n = (seg == 0) ? 4194304 : 1048576;
    const int idx = (blockIdx.x * 256 + threadIdx.x) * 8;
    if (idx < n) {
        float4 lo = *(const float4*)(src + idx);
        float4 hi = *(const float4*)(src + idx + 4);
        *(uint4*)(dst + idx) = pack8(lo, hi);
    }
}

// ---------------------------------------------------------------------------
// Kernel A: GEMM. R27: 512-thread blocks, TWO 64-row m-tiles sharing ONE
// staged B panel (R22 recipe applied to the GEMM). Grid (32,24) = 768 blocks
// x 8 waves = 24 waves/CU — identical TLP to the R22 shape (1536x4). B
// staging traffic halves (384->192 MB); LDS-DMAs/thread/K-step 6 -> 4.
// Waves 0-3 compute m-tile 0, waves 4-7 m-tile 1 — per-wave fragment code
// identical to R22 (bit-identical output). LDS 33 KB -> 4/CU LDS-limit >= 3
// grid-limit: occupancy untouched.
// w==0 (Q) pre-scales by 0.125*log2(e) (attn softmax is bare exp2).
// w==2 (V) stores V^T [B,H,D,S] tau-permuted (tau(p)=((p&3)<<4)|(p>>2)).
// ---------------------------------------------------------------------------
__global__ __launch_bounds__(512) void qkv_rope_kernel(
    const u16* __restrict__ xb, const u16* __restrict__ wb,
    const float2* __restrict__ tab,
    u16* __restrict__ qo, u16* __restrict__ ko, u16* __restrict__ vo)
{
    const int w  = blockIdx.y >> 3;         // 0..2
    const int nb = blockIdx.y & 7;          // 0..7
    const u16* W = wb + w * 1048576;

    // loop phase: As0 4096 + As1 4096 + Bs 8192 u16 = 32 KB
    // epilogue:   Ep[2] of 64x132 u16 (8448 each) = 33 KB overlay
    __shared__ __align__(16) u16 smem[16896];
    u16* As0 = smem;
    u16* As1 = smem + 4096;
    u16* Bs  = smem + 8192;

    const int tid   = threadIdx.x;      // 0..511
    const int lane  = tid & 63;
    const int wid   = tid >> 6;         // 0..7
    const int t     = wid >> 2;         // m-tile 0/1
    const int sub   = wid & 3;
    const int waveM = sub >> 1;         // 0..1 (32-row slice)
    const int waveN = sub & 1;          // 0..1 (64-col slice)
    const int col16 = lane & 15;
    const int quad  = lane >> 4;

    const int m0 = blockIdx.x * 128;    // 128-row super-tile (2 x 64)
    const int n0 = nb * 128;

    f32x4 acc[2][4];
    const f32x4 zero4 = {0.f, 0.f, 0.f, 0.f};
#pragma unroll
    for (int i = 0; i < 2; i++)
#pragma unroll
        for (int j = 0; j < 4; j++) acc[i][j] = zero4;

    const int srow = tid >> 3;          // 0..63
    const int spos = tid & 7;
    const int scg  = spos ^ (srow & 7);
    const u16* Ag = xb + (size_t)m0 * EMB;
    const u16* Bg = W  + (size_t)n0 * EMB;
    u16* myAs = t ? As1 : As0;

    for (int k0 = 0; k0 < EMB; k0 += 64) {
        __syncthreads();
        // A0 / A1: one DMA each (512 threads cover a 64x64 tile)
        lds_dma16(Ag + (size_t)srow * EMB + k0 + scg * 8, As0 + wid * 512);
        lds_dma16(Ag + (size_t)(64 + srow) * EMB + k0 + scg * 8,
                  As1 + wid * 512);
        // B: 2 DMAs (128x64 tile)
#pragma unroll
        for (int j = 0; j < 2; j++) {
            const int c = j * 512 + tid;
            const int row = c >> 3;
            const int pos = c & 7;
            const int cg = pos ^ (row & 7);
            lds_dma16(Bg + (size_t)row * EMB + k0 + cg * 8,
                      Bs + j * 4096 + wid * 512);
        }
        __syncthreads();

        short8 af[2][2], bf[4][2];
#pragma unroll
        for (int mt = 0; mt < 2; mt++) {
            const int r = waveM * 32 + mt * 16 + col16;
#pragma unroll
            for (int ks = 0; ks < 2; ks++) {
                const int p = (ks * 4 + quad) ^ (r & 7);
                af[mt][ks] = *(const short8*)(myAs + r * 64 + p * 8);
            }
        }
#pragma unroll
        for (int nt = 0; nt < 4; nt++) {
            const int r = waveN * 64 + nt * 16 + col16;
#pragma unroll
            for (int ks = 0; ks < 2; ks++) {
                const int p = (ks * 4 + quad) ^ (r & 7);
                bf[nt][ks] = *(const short8*)(Bs + r * 64 + p * 8);
            }
        }
#pragma unroll
        for (int ks = 0; ks < 2; ks++)
#pragma unroll
            for (int mt = 0; mt < 2; mt++)
#pragma unroll
                for (int nt = 0; nt < 4; nt++)
                    acc[mt][nt] = __builtin_amdgcn_mfma_f32_16x16x32_bf16(
                        af[mt][ks], bf[nt][ks], acc[mt][nt], 0, 0, 0);
    }

    // ---- epilogue: per-tile Ep overlay; RoPE + 16B coalesced stores ----
    const float qs = (w == 0) ? 0.18033688011112042f : 1.0f;
    __syncthreads();
    u16 (*Ep)[132] = (u16(*)[132])(smem + t * 8448);
#pragma unroll
    for (int mt = 0; mt < 2; mt++) {
#pragma unroll
        for (int r = 0; r < 4; r++) {
            const int m_local = waveM * 32 + mt * 16 + quad * 4 + r;
            const int s = (m0 + t * 64 + m_local) & 2047;
            if (w == 2) {
#pragma unroll
                for (int nt = 0; nt < 4; nt++)
                    Ep[m_local][waveN * 64 + nt * 16 + col16] =
                        (u16)f2bf_u(acc[mt][nt][r]);
            } else {
#pragma unroll
                for (int nt = 0; nt < 2; nt++) {
                    const int d = nt * 16 + col16;          // [0,32)
                    const float2 cs = tab[s * 32 + d];
                    const float lo = acc[mt][nt][r];
                    const float hi = acc[mt][nt + 2][r];
                    Ep[m_local][waveN * 64 + d]      =
                        (u16)f2bf_u((lo * cs.x - hi * cs.y) * qs);
                    Ep[m_local][waveN * 64 + d + 32] =
                        (u16)f2bf_u((hi * cs.x + lo * cs.y) * qs);
                }
            }
        }
    }
    __syncthreads();

    const int tid2 = tid & 255;         // lane within the half-block
    const int bt = (m0 + t * 64) >> 11; // batch (tiles never straddle 2048)
    if (w != 2) {
        u16* out = (w == 0) ? qo : ko;
        const int sBase = (m0 + t * 64) & 2047;
#pragma unroll
        for (int j = 0; j < 4; j++) {
            const int g = j * 256 + tid2;       // [0,1024): 2 heads x 64 s x 8
            const int head_local = g >> 9;
            const int sl  = (g >> 3) & 63;
            const int cir = g & 7;
            uint4 val = *(const uint4*)(&Ep[sl][head_local * 64 + cir * 8]);
            const int h = (n0 >> 6) + head_local;
            const size_t base = (((size_t)(bt * H_NUM + h)) * S_LEN + sBase) * 64;
            *(uint4*)(out + base + (size_t)(g & 511) * 8) = val;
        }
    } else {
        // V^T store: vo[((b*16+h)*64+d)*2048 + s]; one tau 64-block per tile
        const int s0 = (m0 + t * 64) & 2047;
#pragma unroll
        for (int j = 0; j < 4; j++) {
            const int g = j * 256 + tid2;       // [0,1024): d_all(128) x sc(8)
            const int d_all = g >> 3;           // 0..127
            const int sc = g & 7;               // s-chunk of 8
            u32 wv[4];
#pragma unroll
            for (int hw = 0; hw < 4; hw++) {
                const int p0 = sc * 8 + hw * 2;
                const int r0 = ((p0 & 3) << 4) | (p0 >> 2);
                const int p1 = p0 + 1;
                const int r1 = ((p1 & 3) << 4) | (p1 >> 2);
                wv[hw] = (u32)Ep[r0][d_all] | ((u32)Ep[r1][d_all] << 16);
            }
            const int h = (n0 >> 6) + (d_all >> 6);
            const int d = d_all & 63;
            *(uint4*)(vo + ((size_t)(bt * H_NUM + h) * 64 + d) * 2048 + s0 + sc * 8) =
                make_uint4(wv[0], wv[1], wv[2], wv[3]);
        }
    }
}

// ---------------------------------------------------------------------------
// Kernel B: causal flash attention. R26 (verified): kv-parity split — both
// wave groups process both q-tiles (qbA=p, qbB=31-p); group X even kv-tiles,
// Y odd; fixed-max softmax => additive partials; one cross-group LDS merge.
// R24 pair staging (two kv-tiles per barrier interval), 80 KB, 2 blocks/CU.
// ---------------------------------------------------------------------------
__global__ __launch_bounds__(512, 4) void attn_kernel(
    const u16* __restrict__ q, const u16* __restrict__ k,
    const u16* __restrict__ v, u16* __restrict__ ctx)
{
    __shared__ __align__(16) u16 QP[2][64 * 64];     // Q staging -> P/O scratch
    __shared__ __align__(16) u16 Ks[2][2][64 * 64];  // [buf][slot] K tiles
    __shared__ __align__(16) u16 VTs[2][2][64 * 64]; // [buf][slot] V^T tiles

    const int tid   = threadIdx.x;      // 0..511
    const int lane  = tid & 63;
    const int wid   = tid >> 6;         // 0..7
    const int w4    = wid & 3;          // row-slice [w4*16,+16) of BOTH tiles
    const int g     = wid >> 2;         // kv-parity group: 0 = even, 1 = odd
    const int col16 = lane & 15;
    const int quad  = lane >> 4;

    const int bh = blockIdx.x;
    const int p  = blockIdx.y;           // pair index 0..15
    const int qbA = p;                   // short tile: 0..15
    const int qbB = 31 - p;              // long tile: 16..31
    const int qBaseA = qbA * 64;
    const int qBaseB = qbB * 64;
    const size_t bhOff = (size_t)bh * S_LEN * D_DIM;   // same for V^T (64*2048)

    const int srow = tid >> 3;          // 0..63 (512 threads cover full tile)
    const int spos = tid & 7;
    const int scg  = spos ^ (srow & 7);

    auto stage = [&](int kt, int buf, int slot) {
        lds_dma16(k + bhOff + (size_t)(kt * 64 + srow) * 64 + scg * 8,
                  &Ks[buf][slot][wid * 512]);
        lds_dma16(v + bhOff + (size_t)srow * 2048 + kt * 64 + scg * 8,
                  &VTs[buf][slot][wid * 512]);
    };

    // prologue: stage pair {0,1} (qbB>=16 so tile 1 exists) + both Q tiles
    stage(0, 0, 0);
    stage(1, 0, 1);
    {
        const int stBase = g ? qBaseB : qBaseA;   // X stages Q_A, Y stages Q_B
        const int r5 = srow & 31;
#pragma unroll
        for (int j = 0; j < 2; j++) {
            const int rl = j * 32 + r5;
            const int cg = spos ^ (rl & 7);
            lds_dma16(q + bhOff + (size_t)(stBase + rl) * 64 + cg * 8,
                      QP[g] + (j * 32 + w4 * 8) * 64);
        }
    }
    __syncthreads();   // Q_A + Q_B + pair {0,1} ready

    // every wave reads fragments of BOTH q-tiles for its 16 rows
    short8 qfA[2], qfB[2];
    {
        const int rq = w4 * 16 + col16;
#pragma unroll
        for (int ks = 0; ks < 2; ks++) {
            const int c = (ks * 4 + quad) ^ (rq & 7);
            qfA[ks] = *(const short8*)(QP[0] + rq * 64 + c * 8);
            qfB[ks] = *(const short8*)(QP[1] + rq * 64 + c * 8);
        }
    }

    // wave-private 16x64 P/O scratch (overlays the now-dead Q staging)
    u16* myP = ((u16*)QP) + wid * 1024;

    // all-ones bf16 B-fragment for row-sum MFMA (bf16 1.0 = 0x3F80)
    const short ONE = (short)0x3F80;
    const short8 onesf = {ONE, ONE, ONE, ONE, ONE, ONE, ONE, ONE};

    f32x4 OA[4], OB[4];
    const f32x4 zero4 = {0.f, 0.f, 0.f, 0.f};
#pragma unroll
    for (int j = 0; j < 4; j++) { OA[j] = zero4; OB[j] = zero4; }
    f32x4 laccA = zero4, laccB = zero4;

    // one kv-tile vs one q-tile: QK^T -> exp2 -> P-LDS -> PV (verified body)
    auto proc = [&](const short8* qf, f32x4* O, f32x4& lacc,
                    int qBase, int qb, int kt, int bufv) {
        const int sl = g;
        f32x4 sc[4];
#pragma unroll
        for (int nt = 0; nt < 4; nt++) sc[nt] = zero4;
#pragma unroll
        for (int ks = 0; ks < 2; ks++) {
            short8 kf[4];
#pragma unroll
            for (int nt = 0; nt < 4; nt++) {
                const int rk = nt * 16 + col16;
                const int c = (ks * 4 + quad) ^ (rk & 7);
                kf[nt] = *(const short8*)(&Ks[bufv][sl][rk * 64 + c * 8]);
            }
            __builtin_amdgcn_s_setprio(1);
#pragma unroll
            for (int nt = 0; nt < 4; nt++)
                sc[nt] = __builtin_amdgcn_mfma_f32_16x16x32_bf16(
                    qf[ks], kf[nt], sc[nt], 0, 0, 0);
            __builtin_amdgcn_s_setprio(0);
        }

        if (kt == qb) {
#pragma unroll
            for (int r = 0; r < 4; r++) {
                const int qg = qBase + w4 * 16 + quad * 4 + r;
#pragma unroll
                for (int nt = 0; nt < 4; nt++) {
                    const int kg = kt * 64 + nt * 16 + col16;
                    float pv = __builtin_amdgcn_exp2f(sc[nt][r]);
                    if (kg > qg) pv = 0.f;
                    sc[nt][r] = pv;
                }
            }
        } else {
#pragma unroll
            for (int r = 0; r < 4; r++)
#pragma unroll
                for (int nt = 0; nt < 4; nt++)
                    sc[nt][r] = __builtin_amdgcn_exp2f(sc[nt][r]);
        }

        // P -> wave-private scratch rows 0..15, b64 tau-order
#pragma unroll
        for (int r = 0; r < 4; r++) {
            const int ml = quad * 4 + r;
            const u32 lo = pack2t(sc[0][r], sc[1][r]);
            const u32 hi = pack2t(sc[2][r], sc[3][r]);
            *(uint2*)(myP + ml * 64 +
                      (((col16 >> 1) ^ (ml & 7)) * 8 + (col16 & 1) * 4)) =
                make_uint2(lo, hi);
        }

#pragma unroll
        for (int ks = 0; ks < 2; ks++) {
            short8 pf, vf[4];
            {
                const int c = (ks * 4 + quad) ^ (col16 & 7);
                pf = *(const short8*)(myP + col16 * 64 + c * 8);
            }
#pragma unroll
            for (int dt = 0; dt < 4; dt++) {
                const int d = dt * 16 + col16;
                const int c = (ks * 4 + quad) ^ (d & 7);
                vf[dt] = *(const short8*)(&VTs[bufv][sl][d * 64 + c * 8]);
            }
            __builtin_amdgcn_s_setprio(1);
#pragma unroll
            for (int dt = 0; dt < 4; dt++)
                O[dt] = __builtin_amdgcn_mfma_f32_16x16x32_bf16(
                    pf, vf[dt], O[dt], 0, 0, 0);
            lacc = __builtin_amdgcn_mfma_f32_16x16x32_bf16(
                pf, onesf, lacc, 0, 0, 0);
            __builtin_amdgcn_s_setprio(0);
        }
    };

    int buf = 0;
    for (int kt0 = 0; kt0 <= qbB; kt0 += 2) {
        // unconditional: at kt0==0 orders qf reads before P-scratch writes;
        // afterwards drains the prefetched pair and fences prev-buf reads
        __syncthreads();
        if (kt0 + 2 <= qbB) {
            stage(kt0 + 2, buf ^ 1, 0);
            if (kt0 + 3 <= qbB) stage(kt0 + 3, buf ^ 1, 1);
        }
        const int kt = kt0 + g;       // this group's kv-tile (parity g)
        if (kt <= qbB) {
            proc(qfB, OB, laccB, qBaseB, qbB, kt, buf);
            if (kt <= qbA)
                proc(qfA, OA, laccA, qBaseA, qbA, kt, buf);
        }
        buf ^= 1;
    }

    // ---- cross-group merge: X finalizes A (exports B), Y finalizes B ----
    __syncthreads();   // all K/V buffer reads done; overlays now safe
    {
        // region per w4: 1296 f32 (lane stride 20 f32 to spread banks)
        float* eb = (g ? (float*)&VTs[0][0][0] : (float*)&Ks[0][0][0])
                    + w4 * 1296;
        f32x4* eO = g ? OA : OB;          // export the tile we don't finalize
        f32x4  eL = g ? laccA : laccB;
#pragma unroll
        for (int dt = 0; dt < 4; dt++)
            *(f32x4*)(eb + lane * 20 + dt * 4) = eO[dt];
        if (col16 == 0)
            *(f32x4*)(eb + 1280 + quad * 4) = eL;
    }
    __syncthreads();
    f32x4 myO[4];
    f32x4 myL;
    {
        float* ib = (g ? (float*)&Ks[0][0][0] : (float*)&VTs[0][0][0])
                    + w4 * 1296;
#pragma unroll
        for (int dt = 0; dt < 4; dt++) {
            const f32x4 pp = *(const f32x4*)(ib + lane * 20 + dt * 4);
            myO[dt] = (g ? OB[dt] : OA[dt]) + pp;
        }
        const f32x4 lp = *(const f32x4*)(ib + 1280 + quad * 4);
        myL = (g ? laccB : laccA) + lp;
    }

    // O epilogue: each wave finalizes 16 rows of its tile via its scratch
    const int b = bh >> 4, h = bh & 15;
    const int outBase = g ? qBaseB : qBaseA;
#pragma unroll
    for (int r = 0; r < 4; r++) {
        const int ml = quad * 4 + r;
        const float inv = __builtin_amdgcn_rcpf(myL[r]);
        const u32 lo = pack2t(myO[0][r] * inv, myO[1][r] * inv);
        const u32 hi = pack2t(myO[2][r] * inv, myO[3][r] * inv);
        *(uint2*)(myP + ml * 64 +
                  (((col16 >> 1) ^ (ml & 7)) * 8 + (col16 & 1) * 4)) =
            make_uint2(lo, hi);
    }
#pragma unroll
    for (int j = 0; j < 2; j++) {
        const int gg  = j * 64 + lane;      // 128 chunks: 16 rows x 8 d-chunks
        const int sl = gg >> 3;
        const int cir = gg & 7;
        u32 wv[4];
#pragma unroll
        for (int hw = 0; hw < 4; hw++) {
            const int d0 = cir * 8 + hw * 2;
            const int p0 = ((d0 & 15) << 2) | (d0 >> 4);
            const int d1 = d0 + 1;
            const int p1 = ((d1 & 15) << 2) | (d1 >> 4);
            const u16 v0 = myP[sl * 64 + ((p0 >> 3) ^ (sl & 7)) * 8 + (p0 & 7)];
            const u16 v1 = myP[sl * 64 + ((p1 >> 3) ^ (sl & 7)) * 8 + (p1 & 7)];
            wv[hw] = (u32)v0 | ((u32)v1 << 16);
        }
        const size_t rowbase =
            ((size_t)b * S_LEN + outBase + w4 * 16 + sl) * EMB + h * 64;
        *(uint4*)(ctx + rowbase + cir * 8) = make_uint4(wv[0], wv[1], wv[2], wv[3]);
    }
}

// ---------------------------------------------------------------------------
// Kernel C: out(f32) = ctx * Wo^T. 64x64 tiles, grid (64, 16) = 1024 blocks
// = 4/CU. R25 (kept): BK=128 — 16 barrier intervals, LDS 32 KB, occupancy
// unchanged (grid-limited 4/CU).
// ---------------------------------------------------------------------------
__global__ __launch_bounds__(256) void proj_kernel(
    const u16* __restrict__ X, const u16* __restrict__ W, float* __restrict__ out)
{
    __shared__ __align__(16) u16 smem[16384];   // As 64x128 + Bs 64x128

    const int tid   = threadIdx.x;
    const int lane  = tid & 63;
    const int wid   = tid >> 6;          // 0..3: m-row slice [wid*16, +16)
    const int col16 = lane & 15;
    const int quad  = lane >> 4;

    const int m0 = blockIdx.x * 64;
    const int n0 = blockIdx.y * 64;

    u16* As = smem;
    u16* Bs = smem + 64 * 128;

    f32x4 acc[4];   // [nt] (operand-swapped: lane m = col16, n = quad*4+r)
    const f32x4 zero4 = {0.f, 0.f, 0.f, 0.f};
#pragma unroll
    for (int i = 0; i < 4; i++) acc[i] = zero4;

    // staging decomposition: per round jj, wave covers 4 rows x 16 chunks
    const int srow4 = lane >> 4;        // 0..3 row within wave's 4-row group
    const int pos   = lane & 15;        // chunk position within row
    const u16* Ag = X + (size_t)m0 * EMB;
    const u16* Bg = W + (size_t)n0 * EMB;

    for (int kk = 0; kk < 8; kk++) {
        const int k0 = kk * 128;
        __syncthreads();
#pragma unroll
        for (int jj = 0; jj < 4; jj++) {
            const int row = jj * 16 + wid * 4 + srow4;
            const int cg = (pos & 8) | ((pos & 7) ^ (row & 7));
            lds_dma16(Ag + (size_t)row * EMB + k0 + cg * 8,
                      As + (jj * 16 + wid * 4) * 128);
        }
#pragma unroll
        for (int jj = 0; jj < 4; jj++) {
            const int row = jj * 16 + wid * 4 + srow4;
            const int cg = (pos & 8) | ((pos & 7) ^ (row & 7));
            lds_dma16(Bg + (size_t)row * EMB + k0 + cg * 8,
                      Bs + (jj * 16 + wid * 4) * 128);
        }
        __syncthreads();

#pragma unroll
        for (int half = 0; half < 2; half++) {
            short8 af[2], bf[4][2];
            {
                const int r = wid * 16 + col16;
#pragma unroll
                for (int ks = 0; ks < 2; ks++) {
                    const int p = half * 8 + (((ks * 4 + quad)) ^ (r & 7));
                    af[ks] = *(const short8*)(As + r * 128 + p * 8);
                }
            }
#pragma unroll
            for (int nt = 0; nt < 4; nt++) {
                const int r = nt * 16 + col16;
#pragma unroll
                for (int ks = 0; ks < 2; ks++) {
                    const int p = half * 8 + (((ks * 4 + quad)) ^ (r & 7));
                    bf[nt][ks] = *(const short8*)(Bs + r * 128 + p * 8);
                }
            }
#pragma unroll
            for (int ks = 0; ks < 2; ks++)
#pragma unroll
                for (int nt = 0; nt < 4; nt++)
                    acc[nt] = __builtin_amdgcn_mfma_f32_16x16x32_bf16(
                        bf[nt][ks], af[ks], acc[nt], 0, 0, 0);
        }
    }

#pragma unroll
    for (int nt = 0; nt < 4; nt++) {
        const int m_g = m0 + wid * 16 + col16;
        const int n_g = n0 + nt * 16 + quad * 4;
        *(f32x4*)(out + (size_t)m_g * EMB + n_g) = acc[nt];
    }
}

// ---------------------------------------------------------------------------
extern "C" void kernel_launch(void* const* d_in, const int* in_sizes, int n_in,
                              void* d_out, int out_size, void* d_ws, size_t ws_size,
                              hipStream_t stream)
{
    const float* x  = (const float*)d_in[0];
    const float* Wq = (const float*)d_in[1];
    const float* Wk = (const float*)d_in[2];
    const float* Wv = (const float*)d_in[3];
    const float* Wo = (const float*)d_in[4];

    u16* ws = (u16*)d_ws;
    u16* xb  = ws;
    u16* wb  = ws + 4194304;            // wq,wk,wv contiguous
    u16* wob = ws + 7340032;
    u16* q   = ws + 8388608;
    u16* k   = ws + 12582912;
    u16* v   = ws + 16777216;           // V^T [B,H,D,S], tau-ordered
    u16* ctx = ws + 20971520;
    float2* tab = (float2*)(ws + 25165824);   // 2048x32 float2 = 512 KB

    cast_kernel<<<dim3(2048, 6), 256, 0, stream>>>(x, Wq, Wk, Wv, Wo, ws, tab);
    qkv_rope_kernel<<<dim3(32, 24), 512, 0, stream>>>(xb, wb, tab, q, k, v);
    attn_kernel<<<dim3(32, 16), 512, 0, stream>>>(q, k, v, ctx);
    proj_kernel<<<dim3(64, 16), 256, 0, stream>>>(ctx, wob, (float*)d_out);
}

// Round 12
// 158.279 us; speedup vs baseline: 1.0345x; 1.0345x over previous
//
#include <hip/hip_runtime.h>
#include <hip/hip_bf16.h>

#define H_NUM 16
#define D_DIM 64
#define S_LEN 2048
#define EMB   1024
#define M_TOT 4096   // B * S_LEN

typedef unsigned short u16;
typedef unsigned int   u32;
typedef __attribute__((ext_vector_type(8))) short short8;   // 8 bf16 in 4 VGPRs
typedef __attribute__((ext_vector_type(4))) float f32x4;    // MFMA C/D

__device__ __forceinline__ u32 f2bf_u(float f) {
    u32 u = __float_as_uint(f);
    return (u + 0x7fffu + ((u >> 16) & 1u)) >> 16;   // RNE, low 16 valid
}
__device__ __forceinline__ u32 pack2(float a, float b) {
    return f2bf_u(a) | (f2bf_u(b) << 16);
}
// 1-instr truncating bf16 pack: low16 = bf16(a) (RTZ), high16 = bf16(b) (RTZ)
__device__ __forceinline__ u32 pack2t(float a, float b) {
    return __builtin_amdgcn_perm(__float_as_uint(b), __float_as_uint(a),
                                 0x07060302u);
}
__device__ __forceinline__ uint4 pack8(float4 lo, float4 hi) {
    return make_uint4(pack2(lo.x, lo.y), pack2(lo.z, lo.w),
                      pack2(hi.x, hi.y), pack2(hi.z, hi.w));
}

// async global->LDS, 16B per lane; lds dest = wave-uniform base + lane*16
__device__ __forceinline__ void lds_dma16(const u16* g, u16* l) {
    __builtin_amdgcn_global_load_lds(
        (const __attribute__((address_space(1))) void*)g,
        (__attribute__((address_space(3))) void*)l, 16, 0, 0);
}

// ---------------------------------------------------------------------------
// Kernel 0: cast f32 inputs -> bf16 ws copies; seg 5 builds RoPE cos/sin table
// ---------------------------------------------------------------------------
__global__ __launch_bounds__(256) void cast_kernel(
    const float* __restrict__ x,  const float* __restrict__ Wq,
    const float* __restrict__ Wk, const float* __restrict__ Wv,
    const float* __restrict__ Wo, u16* __restrict__ ws, float2* __restrict__ tab)
{
    const int seg = blockIdx.y;
    if (seg == 5) {
        const int idx = blockIdx.x * 256 + threadIdx.x;
        if (idx < S_LEN * 32) {
            const int s = idx >> 5, d = idx & 31;
            const float ang = (float)s * __expf(-(float)d * 0.28782313662425573f);
            tab[idx] = make_float2(cosf(ang), sinf(ang));
        }
        return;
    }
    const float* src = (seg == 0) ? x : (seg == 1) ? Wq : (seg == 2) ? Wk
                     : (seg == 3) ? Wv : Wo;
    u16* dst = (seg == 0) ? ws : ws + (3 + seg) * 1048576;   // xb@0, W*@4M..7M
    const int n = (seg == 0) ? 4194304 : 1048576;
    const int idx = (blockIdx.x * 256 + threadIdx.x) * 8;
    if (idx < n) {
        float4 lo = *(const float4*)(src + idx);
        float4 hi = *(const float4*)(src + idx + 4);
        *(uint4*)(dst + idx) = pack8(lo, hi);
    }
}

// ---------------------------------------------------------------------------
// Kernel A: GEMM, 64x128 tiles (R19/R22/R26-verified; R27's 512-thread
// shared-B variant regressed: halved independent blocks/CU, which is what
// hides the 2-barrier drain). Grid (64,24) = 1536 blocks = 6/CU, LDS 24 KB.
// w==0 (Q) pre-scales by 0.125*log2(e) (attn softmax is bare exp2).
// w==2 (V) stores V^T [B,H,D,S] tau-permuted (tau(p)=((p&3)<<4)|(p>>2)).
// ---------------------------------------------------------------------------
__global__ __launch_bounds__(256) void qkv_rope_kernel(
    const u16* __restrict__ xb, const u16* __restrict__ wb,
    const float2* __restrict__ tab,
    u16* __restrict__ qo, u16* __restrict__ ko, u16* __restrict__ vo)
{
    const int w  = blockIdx.y >> 3;         // 0..2
    const int nb = blockIdx.y & 7;          // 0..7
    const u16* W = wb + w * 1048576;

    __shared__ __align__(16) u16 smem[12288];   // As 4K + Bs 8K u16; Ep 64x132
    u16* As = smem;
    u16* Bs = smem + 64 * 64;
    u16 (*Ep)[132] = (u16(*)[132])smem;

    const int tid   = threadIdx.x;
    const int lane  = tid & 63;
    const int wid   = tid >> 6;
    const int waveM = wid >> 1;          // 0..1 (32-row slice)
    const int waveN = wid & 1;           // 0..1 (64-col slice)
    const int col16 = lane & 15;
    const int quad  = lane >> 4;

    const int m0 = blockIdx.x * 64;
    const int n0 = nb * 128;

    f32x4 acc[2][4];
    const f32x4 zero4 = {0.f, 0.f, 0.f, 0.f};
#pragma unroll
    for (int i = 0; i < 2; i++)
#pragma unroll
        for (int j = 0; j < 4; j++) acc[i][j] = zero4;

    const int drow = tid >> 3;          // 0..31
    const int dpos = tid & 7;
    const u16* Ag = xb + (size_t)m0 * EMB;
    const u16* Bg = W  + (size_t)n0 * EMB;

    for (int k0 = 0; k0 < EMB; k0 += 64) {
        __syncthreads();
#pragma unroll
        for (int j = 0; j < 2; j++) {
            const int rl = j * 32 + drow;
            const int cg = dpos ^ (rl & 7);
            lds_dma16(Ag + (size_t)rl * EMB + k0 + cg * 8,
                      As + (j * 32 + wid * 8) * 64);
        }
#pragma unroll
        for (int j = 0; j < 4; j++) {
            const int rl = j * 32 + drow;
            const int cg = dpos ^ (rl & 7);
            lds_dma16(Bg + (size_t)rl * EMB + k0 + cg * 8,
                      Bs + (j * 32 + wid * 8) * 64);
        }
        __syncthreads();

        short8 af[2][2], bf[4][2];
#pragma unroll
        for (int mt = 0; mt < 2; mt++) {
            const int r = waveM * 32 + mt * 16 + col16;
#pragma unroll
            for (int ks = 0; ks < 2; ks++) {
                const int p = (ks * 4 + quad) ^ (r & 7);
                af[mt][ks] = *(const short8*)(As + r * 64 + p * 8);
            }
        }
#pragma unroll
        for (int nt = 0; nt < 4; nt++) {
            const int r = waveN * 64 + nt * 16 + col16;
#pragma unroll
            for (int ks = 0; ks < 2; ks++) {
                const int p = (ks * 4 + quad) ^ (r & 7);
                bf[nt][ks] = *(const short8*)(Bs + r * 64 + p * 8);
            }
        }
#pragma unroll
        for (int ks = 0; ks < 2; ks++)
#pragma unroll
            for (int mt = 0; mt < 2; mt++)
#pragma unroll
                for (int nt = 0; nt < 4; nt++)
                    acc[mt][nt] = __builtin_amdgcn_mfma_f32_16x16x32_bf16(
                        af[mt][ks], bf[nt][ks], acc[mt][nt], 0, 0, 0);
    }

    // ---- epilogue: RoPE (table) + LDS round trip + 16B coalesced stores ----
    // Q (w==0) additionally scaled by 0.125*log2(e): attn softmax fma removed.
    const float qs = (w == 0) ? 0.18033688011112042f : 1.0f;
    __syncthreads();
#pragma unroll
    for (int mt = 0; mt < 2; mt++) {
#pragma unroll
        for (int r = 0; r < 4; r++) {
            const int m_local = waveM * 32 + mt * 16 + quad * 4 + r;
            const int s = (m0 + m_local) & 2047;
            if (w == 2) {
#pragma unroll
                for (int nt = 0; nt < 4; nt++)
                    Ep[m_local][waveN * 64 + nt * 16 + col16] =
                        (u16)f2bf_u(acc[mt][nt][r]);
            } else {
#pragma unroll
                for (int nt = 0; nt < 2; nt++) {
                    const int d = nt * 16 + col16;          // [0,32)
                    const float2 cs = tab[s * 32 + d];
                    const float lo = acc[mt][nt][r];
                    const float hi = acc[mt][nt + 2][r];
                    Ep[m_local][waveN * 64 + d]      =
                        (u16)f2bf_u((lo * cs.x - hi * cs.y) * qs);
                    Ep[m_local][waveN * 64 + d + 32] =
                        (u16)f2bf_u((hi * cs.x + lo * cs.y) * qs);
                }
            }
        }
    }
    __syncthreads();

    const int b = m0 >> 11;
    if (w != 2) {
        u16* out = (w == 0) ? qo : ko;
#pragma unroll
        for (int j = 0; j < 4; j++) {
            const int g = j * 256 + tid;        // [0,1024): 2 heads x 64 s x 8
            const int head_local = g >> 9;
            const int sl  = (g >> 3) & 63;
            const int cir = g & 7;
            uint4 val = *(const uint4*)(&Ep[sl][head_local * 64 + cir * 8]);
            const int h = (n0 >> 6) + head_local;
            const size_t base = (((size_t)(b * H_NUM + h)) * S_LEN + (m0 & 2047)) * 64;
            *(uint4*)(out + base + (size_t)(g & 511) * 8) = val;
        }
    } else {
        // V^T store: vo[((b*16+h)*64+d)*2048 + s]; one tau 64-block (s-span 64)
        const int s0 = m0 & 2047;
#pragma unroll
        for (int j = 0; j < 4; j++) {
            const int g = j * 256 + tid;        // [0,1024): d_all(128) x sc(8)
            const int d_all = g >> 3;           // 0..127
            const int sc = g & 7;               // s-chunk of 8
            u32 wv[4];
#pragma unroll
            for (int hw = 0; hw < 4; hw++) {
                const int p0 = sc * 8 + hw * 2;
                const int r0 = ((p0 & 3) << 4) | (p0 >> 2);
                const int p1 = p0 + 1;
                const int r1 = ((p1 & 3) << 4) | (p1 >> 2);
                wv[hw] = (u32)Ep[r0][d_all] | ((u32)Ep[r1][d_all] << 16);
            }
            const int h = (n0 >> 6) + (d_all >> 6);
            const int d = d_all & 63;
            *(uint4*)(vo + ((size_t)(b * H_NUM + h) * 64 + d) * 2048 + s0 + sc * 8) =
                make_uint4(wv[0], wv[1], wv[2], wv[3]);
        }
    }
}

// ---------------------------------------------------------------------------
// Kernel B: causal flash attention. R26 (verified): kv-parity split — both
// wave groups process both q-tiles (qbA=p, qbB=31-p); group X even kv-tiles,
// Y odd; fixed-max softmax => additive partials; one cross-group LDS merge.
// R24 pair staging (two kv-tiles per barrier interval), 80 KB, 2 blocks/CU.
// R28: p-remap for per-CU makespan balance. Dispatch is x-fastest, so CU c
// gets blocks {c, c+256} = y-pair {y0, y0+8}. Intervals i(p)=ceil((32-p)/2);
// old p=y gave pair sums 28..22 (12% imbalance). New p=(y<8)?y:23-y pairs
// {y0, 15-y0}: every CU's sum = 25. Pure remap: same work, same occupancy.
// ---------------------------------------------------------------------------
__global__ __launch_bounds__(512, 4) void attn_kernel(
    const u16* __restrict__ q, const u16* __restrict__ k,
    const u16* __restrict__ v, u16* __restrict__ ctx)
{
    __shared__ __align__(16) u16 QP[2][64 * 64];     // Q staging -> P/O scratch
    __shared__ __align__(16) u16 Ks[2][2][64 * 64];  // [buf][slot] K tiles
    __shared__ __align__(16) u16 VTs[2][2][64 * 64]; // [buf][slot] V^T tiles

    const int tid   = threadIdx.x;      // 0..511
    const int lane  = tid & 63;
    const int wid   = tid >> 6;         // 0..7
    const int w4    = wid & 3;          // row-slice [w4*16,+16) of BOTH tiles
    const int g     = wid >> 2;         // kv-parity group: 0 = even, 1 = odd
    const int col16 = lane & 15;
    const int quad  = lane >> 4;

    const int bh = blockIdx.x;
    const int y  = blockIdx.y;           // 0..15
    const int p  = (y < 8) ? y : (23 - y);   // balanced pair index
    const int qbA = p;                   // short tile: 0..15
    const int qbB = 31 - p;              // long tile: 16..31
    const int qBaseA = qbA * 64;
    const int qBaseB = qbB * 64;
    const size_t bhOff = (size_t)bh * S_LEN * D_DIM;   // same for V^T (64*2048)

    const int srow = tid >> 3;          // 0..63 (512 threads cover full tile)
    const int spos = tid & 7;
    const int scg  = spos ^ (srow & 7);

    auto stage = [&](int kt, int buf, int slot) {
        lds_dma16(k + bhOff + (size_t)(kt * 64 + srow) * 64 + scg * 8,
                  &Ks[buf][slot][wid * 512]);
        lds_dma16(v + bhOff + (size_t)srow * 2048 + kt * 64 + scg * 8,
                  &VTs[buf][slot][wid * 512]);
    };

    // prologue: stage pair {0,1} (qbB>=16 so tile 1 exists) + both Q tiles
    stage(0, 0, 0);
    stage(1, 0, 1);
    {
        const int stBase = g ? qBaseB : qBaseA;   // X stages Q_A, Y stages Q_B
        const int r5 = srow & 31;
#pragma unroll
        for (int j = 0; j < 2; j++) {
            const int rl = j * 32 + r5;
            const int cg = spos ^ (rl & 7);
            lds_dma16(q + bhOff + (size_t)(stBase + rl) * 64 + cg * 8,
                      QP[g] + (j * 32 + w4 * 8) * 64);
        }
    }
    __syncthreads();   // Q_A + Q_B + pair {0,1} ready

    // every wave reads fragments of BOTH q-tiles for its 16 rows
    short8 qfA[2], qfB[2];
    {
        const int rq = w4 * 16 + col16;
#pragma unroll
        for (int ks = 0; ks < 2; ks++) {
            const int c = (ks * 4 + quad) ^ (rq & 7);
            qfA[ks] = *(const short8*)(QP[0] + rq * 64 + c * 8);
            qfB[ks] = *(const short8*)(QP[1] + rq * 64 + c * 8);
        }
    }

    // wave-private 16x64 P/O scratch (overlays the now-dead Q staging)
    u16* myP = ((u16*)QP) + wid * 1024;

    // all-ones bf16 B-fragment for row-sum MFMA (bf16 1.0 = 0x3F80)
    const short ONE = (short)0x3F80;
    const short8 onesf = {ONE, ONE, ONE, ONE, ONE, ONE, ONE, ONE};

    f32x4 OA[4], OB[4];
    const f32x4 zero4 = {0.f, 0.f, 0.f, 0.f};
#pragma unroll
    for (int j = 0; j < 4; j++) { OA[j] = zero4; OB[j] = zero4; }
    f32x4 laccA = zero4, laccB = zero4;

    // one kv-tile vs one q-tile: QK^T -> exp2 -> P-LDS -> PV (verified body)
    auto proc = [&](const short8* qf, f32x4* O, f32x4& lacc,
                    int qBase, int qb, int kt, int bufv) {
        const int sl = g;
        f32x4 sc[4];
#pragma unroll
        for (int nt = 0; nt < 4; nt++) sc[nt] = zero4;
#pragma unroll
        for (int ks = 0; ks < 2; ks++) {
            short8 kf[4];
#pragma unroll
            for (int nt = 0; nt < 4; nt++) {
                const int rk = nt * 16 + col16;
                const int c = (ks * 4 + quad) ^ (rk & 7);
                kf[nt] = *(const short8*)(&Ks[bufv][sl][rk * 64 + c * 8]);
            }
            __builtin_amdgcn_s_setprio(1);
#pragma unroll
            for (int nt = 0; nt < 4; nt++)
                sc[nt] = __builtin_amdgcn_mfma_f32_16x16x32_bf16(
                    qf[ks], kf[nt], sc[nt], 0, 0, 0);
            __builtin_amdgcn_s_setprio(0);
        }

        if (kt == qb) {
#pragma unroll
            for (int r = 0; r < 4; r++) {
                const int qg = qBase + w4 * 16 + quad * 4 + r;
#pragma unroll
                for (int nt = 0; nt < 4; nt++) {
                    const int kg = kt * 64 + nt * 16 + col16;
                    float pv = __builtin_amdgcn_exp2f(sc[nt][r]);
                    if (kg > qg) pv = 0.f;
                    sc[nt][r] = pv;
                }
            }
        } else {
#pragma unroll
            for (int r = 0; r < 4; r++)
#pragma unroll
                for (int nt = 0; nt < 4; nt++)
                    sc[nt][r] = __builtin_amdgcn_exp2f(sc[nt][r]);
        }

        // P -> wave-private scratch rows 0..15, b64 tau-order
#pragma unroll
        for (int r = 0; r < 4; r++) {
            const int ml = quad * 4 + r;
            const u32 lo = pack2t(sc[0][r], sc[1][r]);
            const u32 hi = pack2t(sc[2][r], sc[3][r]);
            *(uint2*)(myP + ml * 64 +
                      (((col16 >> 1) ^ (ml & 7)) * 8 + (col16 & 1) * 4)) =
                make_uint2(lo, hi);
        }

#pragma unroll
        for (int ks = 0; ks < 2; ks++) {
            short8 pf, vf[4];
            {
                const int c = (ks * 4 + quad) ^ (col16 & 7);
                pf = *(const short8*)(myP + col16 * 64 + c * 8);
            }
#pragma unroll
            for (int dt = 0; dt < 4; dt++) {
                const int d = dt * 16 + col16;
                const int c = (ks * 4 + quad) ^ (d & 7);
                vf[dt] = *(const short8*)(&VTs[bufv][sl][d * 64 + c * 8]);
            }
            __builtin_amdgcn_s_setprio(1);
#pragma unroll
            for (int dt = 0; dt < 4; dt++)
                O[dt] = __builtin_amdgcn_mfma_f32_16x16x32_bf16(
                    pf, vf[dt], O[dt], 0, 0, 0);
            lacc = __builtin_amdgcn_mfma_f32_16x16x32_bf16(
                pf, onesf, lacc, 0, 0, 0);
            __builtin_amdgcn_s_setprio(0);
        }
    };

    int buf = 0;
    for (int kt0 = 0; kt0 <= qbB; kt0 += 2) {
        // unconditional: at kt0==0 orders qf reads before P-scratch writes;
        // afterwards drains the prefetched pair and fences prev-buf reads
        __syncthreads();
        if (kt0 + 2 <= qbB) {
            stage(kt0 + 2, buf ^ 1, 0);
            if (kt0 + 3 <= qbB) stage(kt0 + 3, buf ^ 1, 1);
        }
        const int kt = kt0 + g;       // this group's kv-tile (parity g)
        if (kt <= qbB) {
            proc(qfB, OB, laccB, qBaseB, qbB, kt, buf);
            if (kt <= qbA)
                proc(qfA, OA, laccA, qBaseA, qbA, kt, buf);
        }
        buf ^= 1;
    }

    // ---- cross-group merge: X finalizes A (exports B), Y finalizes B ----
    __syncthreads();   // all K/V buffer reads done; overlays now safe
    {
        // region per w4: 1296 f32 (lane stride 20 f32 to spread banks)
        float* eb = (g ? (float*)&VTs[0][0][0] : (float*)&Ks[0][0][0])
                    + w4 * 1296;
        f32x4* eO = g ? OA : OB;          // export the tile we don't finalize
        f32x4  eL = g ? laccA : laccB;
#pragma unroll
        for (int dt = 0; dt < 4; dt++)
            *(f32x4*)(eb + lane * 20 + dt * 4) = eO[dt];
        if (col16 == 0)
            *(f32x4*)(eb + 1280 + quad * 4) = eL;
    }
    __syncthreads();
    f32x4 myO[4];
    f32x4 myL;
    {
        float* ib = (g ? (float*)&Ks[0][0][0] : (float*)&VTs[0][0][0])
                    + w4 * 1296;
#pragma unroll
        for (int dt = 0; dt < 4; dt++) {
            const f32x4 pp = *(const f32x4*)(ib + lane * 20 + dt * 4);
            myO[dt] = (g ? OB[dt] : OA[dt]) + pp;
        }
        const f32x4 lp = *(const f32x4*)(ib + 1280 + quad * 4);
        myL = (g ? laccB : laccA) + lp;
    }

    // O epilogue: each wave finalizes 16 rows of its tile via its scratch
    const int b = bh >> 4, h = bh & 15;
    const int outBase = g ? qBaseB : qBaseA;
#pragma unroll
    for (int r = 0; r < 4; r++) {
        const int ml = quad * 4 + r;
        const float inv = __builtin_amdgcn_rcpf(myL[r]);
        const u32 lo = pack2t(myO[0][r] * inv, myO[1][r] * inv);
        const u32 hi = pack2t(myO[2][r] * inv, myO[3][r] * inv);
        *(uint2*)(myP + ml * 64 +
                  (((col16 >> 1) ^ (ml & 7)) * 8 + (col16 & 1) * 4)) =
            make_uint2(lo, hi);
    }
#pragma unroll
    for (int j = 0; j < 2; j++) {
        const int gg  = j * 64 + lane;      // 128 chunks: 16 rows x 8 d-chunks
        const int sl = gg >> 3;
        const int cir = gg & 7;
        u32 wv[4];
#pragma unroll
        for (int hw = 0; hw < 4; hw++) {
            const int d0 = cir * 8 + hw * 2;
            const int p0 = ((d0 & 15) << 2) | (d0 >> 4);
            const int d1 = d0 + 1;
            const int p1 = ((d1 & 15) << 2) | (d1 >> 4);
            const u16 v0 = myP[sl * 64 + ((p0 >> 3) ^ (sl & 7)) * 8 + (p0 & 7)];
            const u16 v1 = myP[sl * 64 + ((p1 >> 3) ^ (sl & 7)) * 8 + (p1 & 7)];
            wv[hw] = (u32)v0 | ((u32)v1 << 16);
        }
        const size_t rowbase =
            ((size_t)b * S_LEN + outBase + w4 * 16 + sl) * EMB + h * 64;
        *(uint4*)(ctx + rowbase + cir * 8) = make_uint4(wv[0], wv[1], wv[2], wv[3]);
    }
}

// ---------------------------------------------------------------------------
// Kernel C: out(f32) = ctx * Wo^T. 64x64 tiles, grid (64, 16) = 1024 blocks
// = 4/CU. R25 (kept): BK=128 — 16 barrier intervals, LDS 32 KB, occupancy
// unchanged (grid-limited 4/CU).
// ---------------------------------------------------------------------------
__global__ __launch_bounds__(256) void proj_kernel(
    const u16* __restrict__ X, const u16* __restrict__ W, float* __restrict__ out)
{
    __shared__ __align__(16) u16 smem[16384];   // As 64x128 + Bs 64x128

    const int tid   = threadIdx.x;
    const int lane  = tid & 63;
    const int wid   = tid >> 6;          // 0..3: m-row slice [wid*16, +16)
    const int col16 = lane & 15;
    const int quad  = lane >> 4;

    const int m0 = blockIdx.x * 64;
    const int n0 = blockIdx.y * 64;

    u16* As = smem;
    u16* Bs = smem + 64 * 128;

    f32x4 acc[4];   // [nt] (operand-swapped: lane m = col16, n = quad*4+r)
    const f32x4 zero4 = {0.f, 0.f, 0.f, 0.f};
#pragma unroll
    for (int i = 0; i < 4; i++) acc[i] = zero4;

    // staging decomposition: per round jj, wave covers 4 rows x 16 chunks
    const int srow4 = lane >> 4;        // 0..3 row within wave's 4-row group
    const int pos   = lane & 15;        // chunk position within row
    const u16* Ag = X + (size_t)m0 * EMB;
    const u16* Bg = W + (size_t)n0 * EMB;

    for (int kk = 0; kk < 8; kk++) {
        const int k0 = kk * 128;
        __syncthreads();
#pragma unroll
        for (int jj = 0; jj < 4; jj++) {
            const int row = jj * 16 + wid * 4 + srow4;
            const int cg = (pos & 8) | ((pos & 7) ^ (row & 7));
            lds_dma16(Ag + (size_t)row * EMB + k0 + cg * 8,
                      As + (jj * 16 + wid * 4) * 128);
        }
#pragma unroll
        for (int jj = 0; jj < 4; jj++) {
            const int row = jj * 16 + wid * 4 + srow4;
            const int cg = (pos & 8) | ((pos & 7) ^ (row & 7));
            lds_dma16(Bg + (size_t)row * EMB + k0 + cg * 8,
                      Bs + (jj * 16 + wid * 4) * 128);
        }
        __syncthreads();

#pragma unroll
        for (int half = 0; half < 2; half++) {
            short8 af[2], bf[4][2];
            {
                const int r = wid * 16 + col16;
#pragma unroll
                for (int ks = 0; ks < 2; ks++) {
                    const int p = half * 8 + (((ks * 4 + quad)) ^ (r & 7));
                    af[ks] = *(const short8*)(As + r * 128 + p * 8);
                }
            }
#pragma unroll
            for (int nt = 0; nt < 4; nt++) {
                const int r = nt * 16 + col16;
#pragma unroll
                for (int ks = 0; ks < 2; ks++) {
                    const int p = half * 8 + (((ks * 4 + quad)) ^ (r & 7));
                    bf[nt][ks] = *(const short8*)(Bs + r * 128 + p * 8);
                }
            }
#pragma unroll
            for (int ks = 0; ks < 2; ks++)
#pragma unroll
                for (int nt = 0; nt < 4; nt++)
                    acc[nt] = __builtin_amdgcn_mfma_f32_16x16x32_bf16(
                        bf[nt][ks], af[ks], acc[nt], 0, 0, 0);
        }
    }

#pragma unroll
    for (int nt = 0; nt < 4; nt++) {
        const int m_g = m0 + wid * 16 + col16;
        const int n_g = n0 + nt * 16 + quad * 4;
        *(f32x4*)(out + (size_t)m_g * EMB + n_g) = acc[nt];
    }
}

// ---------------------------------------------------------------------------
extern "C" void kernel_launch(void* const* d_in, const int* in_sizes, int n_in,
                              void* d_out, int out_size, void* d_ws, size_t ws_size,
                              hipStream_t stream)
{
    const float* x  = (const float*)d_in[0];
    const float* Wq = (const float*)d_in[1];
    const float* Wk = (const float*)d_in[2];
    const float* Wv = (const float*)d_in[3];
    const float* Wo = (const float*)d_in[4];

    u16* ws = (u16*)d_ws;
    u16* xb  = ws;
    u16* wb  = ws + 4194304;            // wq,wk,wv contiguous
    u16* wob = ws + 7340032;
    u16* q   = ws + 8388608;
    u16* k   = ws + 12582912;
    u16* v   = ws + 16777216;           // V^T [B,H,D,S], tau-ordered
    u16* ctx = ws + 20971520;
    float2* tab = (float2*)(ws + 25165824);   // 2048x32 float2 = 512 KB

    cast_kernel<<<dim3(2048, 6), 256, 0, stream>>>(x, Wq, Wk, Wv, Wo, ws, tab);
    qkv_rope_kernel<<<dim3(64, 24), 256, 0, stream>>>(xb, wb, tab, q, k, v);
    attn_kernel<<<dim3(32, 16), 512, 0, stream>>>(q, k, v, ctx);
    proj_kernel<<<dim3(64, 16), 256, 0, stream>>>(ctx, wob, (float*)d_out);
}